// Round 3
// baseline (44.844 us; speedup 1.0000x reference)
//
#include <hip/hip_runtime.h>

// out[b,u] = tanh( exp( max_i x[b,i]*W[i,u] ) - 1 + bias[u] )
// exp monotonic -> max commutes -> max-times "GEMM" + transcendental epilogue.
//
// Dataflow (no LDS, no barriers):
//   wave = 4 batch rows x 64 units (lane = unit)
//   x[row][k] : wave-uniform -> s_load into SGPRs (zero vector cost)
//   W[k][u]   : per-lane coalesced dword loads; all 4 waves of a block read the
//               SAME W stream -> L1 hits. W = 1 MB, L2-resident.
//   4096 waves = 4 waves/SIMD for latency hiding; KU=8 double-buffer, loop kept
//   rolled so the prefetch structure survives codegen.

#define BATCH 2048
#define INDIM 512
#define UNITS 512

#define M  4     // rows per wave
#define KU 8     // k-unroll / prefetch block

__global__ __launch_bounds__(256) void maxexp_kernel(
    const float* __restrict__ x,     // [BATCH][INDIM]
    const float* __restrict__ W,     // [INDIM][UNITS]
    const float* __restrict__ bias,  // [UNITS]
    float* __restrict__ out)         // [BATCH][UNITS]
{
    // 1024 blocks; bijective XCD swizzle (1024 % 8 == 0): each XCD gets a
    // contiguous band of 16 row-groups x all 8 unit-tiles -> x fetched ~once.
    const int g    = blockIdx.y * gridDim.x + blockIdx.x;   // 0..1023
    const int swz  = (g & 7) * 128 + (g >> 3);
    const int bx   = swz & 7;                               // unit tile 0..7
    const int by   = swz >> 3;                              // row group 0..127

    const int lane = threadIdx.x & 63;
    const int wv   = __builtin_amdgcn_readfirstlane(threadIdx.x >> 6); // 0..3
    const int u    = bx * 64 + lane;                        // unit (per-lane)
    const int b0   = by * 16 + wv * M;                      // first row (uniform)

    const float* xrow = x + (size_t)b0 * INDIM;             // uniform base
    const float* wcol = W + u;                              // per-lane base

    float acc[M];
#pragma unroll
    for (int m = 0; m < M; ++m) acc[m] = -3.4e38f;

    float wA[KU], wB[KU];
    float xA[M * KU], xB[M * KU];

#define LOADW(dst, kbi)                                                   \
    {                                                                     \
        const float* wp = wcol + (size_t)(kbi) * KU * UNITS;              \
        _Pragma("unroll")                                                 \
        for (int j = 0; j < KU; ++j) (dst)[j] = wp[(size_t)j * UNITS];    \
    }

#define LOADX(dst, kbi)                                                   \
    {                                                                     \
        const float* xp = xrow + (kbi) * KU;                              \
        _Pragma("unroll")                                                 \
        for (int m = 0; m < M; ++m)                                       \
            _Pragma("unroll")                                             \
            for (int j = 0; j < KU; ++j)                                  \
                (dst)[m * KU + j] = xp[m * INDIM + j];                    \
    }

#define COMPUTE(wreg, xreg)                                               \
    {                                                                     \
        _Pragma("unroll")                                                 \
        for (int m = 0; m < M; ++m)                                       \
            _Pragma("unroll")                                             \
            for (int t = 0; t < KU / 2; ++t) {                            \
                const float p0 = (xreg)[m * KU + 2 * t]     * (wreg)[2 * t];     \
                const float p1 = (xreg)[m * KU + 2 * t + 1] * (wreg)[2 * t + 1]; \
                acc[m] = fmaxf(fmaxf(acc[m], p0), p1);                    \
            }                                                             \
    }

    const int NKB = INDIM / KU;   // 64
    LOADW(wA, 0); LOADX(xA, 0);
#pragma unroll 1
    for (int kb = 0; kb < NKB - 2; kb += 2) {
        LOADW(wB, kb + 1); LOADX(xB, kb + 1);
        COMPUTE(wA, xA);
        LOADW(wA, kb + 2); LOADX(xA, kb + 2);
        COMPUTE(wB, xB);
    }
    LOADW(wB, NKB - 1); LOADX(xB, NKB - 1);
    COMPUTE(wA, xA);
    COMPUTE(wB, xB);

    // epilogue: tanh(exp(m) - 1 + bias)
    const float bv = bias[u];
#pragma unroll
    for (int m = 0; m < M; ++m) {
        const float p = __expf(acc[m]) - 1.0f + bv;
        const float e = __expf(2.0f * p);
        out[(size_t)(b0 + m) * UNITS + u] = 1.0f - 2.0f / (e + 1.0f);
    }
#undef LOADW
#undef LOADX
#undef COMPUTE
}

extern "C" void kernel_launch(void* const* d_in, const int* in_sizes, int n_in,
                              void* d_out, int out_size, void* d_ws, size_t ws_size,
                              hipStream_t stream) {
    const float* x    = (const float*)d_in[0];
    const float* W    = (const float*)d_in[1];
    const float* bias = (const float*)d_in[2];
    float* out = (float*)d_out;

    dim3 grid(UNITS / 64, BATCH / (4 * M));   // (8, 128) = 1024 blocks = 4096 waves
    dim3 block(256);                          // 4 waves/block
    maxexp_kernel<<<grid, block, 0, stream>>>(x, W, bias, out);
}

// Round 4
// 31.285 us; speedup vs baseline: 1.4334x; 1.4334x over previous
//
#include <hip/hip_runtime.h>

// out[b,u] = tanh( exp( max_i x[b,i]*W[i,u] ) - 1 + bias[u] )
// exp monotonic -> max commutes -> max-times "GEMM" + transcendental epilogue.
//
// Structure: W RESIDENT IN VGPRs. Block = 8 waves x 64 units (lane = unit).
//   wave wv holds W[wv*64 .. wv*64+63][u] in 64 VGPRs (preloaded once, coalesced).
//   x rows are wave-uniform -> s_load into SGPRs (scalar pipe; no VMEM).
//   Steady state: pure v_mul + v_max3 from registers. Zero vector loads.
//   Per 16-row group: 32KB LDS 8-way max combine + exp/tanh epilogue.

#define BATCH 2048
#define INDIM 512
#define UNITS 512

#define KC 64   // k-chunk per wave (W-resident VGPRs)
#define RB 32   // rows per block
#define RG 16   // rows per accumulation group
#define NW 8    // waves per block (NW*KC == INDIM)

__global__ __launch_bounds__(512, 4) void maxexp_kernel(
    const float* __restrict__ x,     // [BATCH][INDIM]
    const float* __restrict__ W,     // [INDIM][UNITS]
    const float* __restrict__ bias,  // [UNITS]
    float* __restrict__ out)         // [BATCH][UNITS]
{
    __shared__ float part[RG][NW][64];   // 32 KB

    // bijective XCD swizzle: all 8 u-tiles of a row-band land on one XCD
    // (f%8 == band%8 assuming round-robin block->XCD).
    const int f    = blockIdx.x;          // 0..511
    const int r    = f & 7;
    const int q    = f >> 3;              // 0..63
    const int band = r + 8 * (q & 7);     // 0..63
    const int ut   = q >> 3;              // 0..7

    const int lane = threadIdx.x & 63;
    const int wv   = __builtin_amdgcn_readfirstlane(threadIdx.x >> 6); // 0..7
    const int u    = ut * 64 + lane;      // unit (per-lane)
    const int k0   = wv * KC;             // k-chunk base (uniform)
    const int b0   = band * RB;           // first row (uniform)

    // ---- preload W chunk into registers: W[k0+j][u] ----
    float wreg[KC];
    {
        const float* wp = W + (size_t)k0 * UNITS + u;
#pragma unroll
        for (int j = 0; j < KC; ++j) wreg[j] = wp[(size_t)j * UNITS];
    }

    const float* xb = x + (size_t)b0 * INDIM + k0;   // uniform base
    const float bv  = bias[u];

#pragma unroll 1
    for (int g = 0; g < RB / RG; ++g) {
        float acc[RG];

        // ---- main compute: 16 rows, all from SGPR(x) * VGPR(W) ----
#pragma unroll
        for (int t = 0; t < RG; ++t) {
            const float* xr = xb + (size_t)(g * RG + t) * INDIM;  // uniform
            float mA = -3.4e38f, mB = -3.4e38f;   // two chains (dep-depth /2)
#pragma unroll
            for (int qq = 0; qq < 4; ++qq) {
                const float4 a0 = *reinterpret_cast<const float4*>(xr + qq * 16 + 0);
                const float4 a1 = *reinterpret_cast<const float4*>(xr + qq * 16 + 4);
                const float4 a2 = *reinterpret_cast<const float4*>(xr + qq * 16 + 8);
                const float4 a3 = *reinterpret_cast<const float4*>(xr + qq * 16 + 12);
                const int j0 = qq * 16;
                float& mm = (qq < 2) ? mA : mB;
                {
                    const float p0 = a0.x * wreg[j0 + 0], p1 = a0.y * wreg[j0 + 1];
                    mm = fmaxf(fmaxf(mm, p0), p1);
                    const float p2 = a0.z * wreg[j0 + 2], p3 = a0.w * wreg[j0 + 3];
                    mm = fmaxf(fmaxf(mm, p2), p3);
                }
                {
                    const float p0 = a1.x * wreg[j0 + 4], p1 = a1.y * wreg[j0 + 5];
                    mm = fmaxf(fmaxf(mm, p0), p1);
                    const float p2 = a1.z * wreg[j0 + 6], p3 = a1.w * wreg[j0 + 7];
                    mm = fmaxf(fmaxf(mm, p2), p3);
                }
                {
                    const float p0 = a2.x * wreg[j0 + 8], p1 = a2.y * wreg[j0 + 9];
                    mm = fmaxf(fmaxf(mm, p0), p1);
                    const float p2 = a2.z * wreg[j0 + 10], p3 = a2.w * wreg[j0 + 11];
                    mm = fmaxf(fmaxf(mm, p2), p3);
                }
                {
                    const float p0 = a3.x * wreg[j0 + 12], p1 = a3.y * wreg[j0 + 13];
                    mm = fmaxf(fmaxf(mm, p0), p1);
                    const float p2 = a3.z * wreg[j0 + 14], p3 = a3.w * wreg[j0 + 15];
                    mm = fmaxf(fmaxf(mm, p2), p3);
                }
            }
            acc[t] = fmaxf(mA, mB);
        }

        // ---- 8-way cross-wave max combine via LDS ----
        __syncthreads();   // protect LDS reuse from previous group's reads
#pragma unroll
        for (int t = 0; t < RG; ++t) part[t][wv][lane] = acc[t];
        __syncthreads();

        // each wave reduces 2 rows, applies epilogue, stores
#pragma unroll
        for (int i = 0; i < 2; ++i) {
            const int t = 2 * wv + i;
            const float p0 = part[t][0][lane], p1 = part[t][1][lane];
            const float p2 = part[t][2][lane], p3 = part[t][3][lane];
            const float p4 = part[t][4][lane], p5 = part[t][5][lane];
            const float p6 = part[t][6][lane], p7 = part[t][7][lane];
            float m = fmaxf(fmaxf(fmaxf(p0, p1), fmaxf(p2, p3)),
                            fmaxf(fmaxf(p4, p5), fmaxf(p6, p7)));
            const float pp = __expf(m) - 1.0f + bv;
            const float e  = __expf(2.0f * pp);
            out[(size_t)(b0 + g * RG + t) * UNITS + u] = 1.0f - 2.0f / (e + 1.0f);
        }
    }
}

extern "C" void kernel_launch(void* const* d_in, const int* in_sizes, int n_in,
                              void* d_out, int out_size, void* d_ws, size_t ws_size,
                              hipStream_t stream) {
    const float* x    = (const float*)d_in[0];
    const float* W    = (const float*)d_in[1];
    const float* bias = (const float*)d_in[2];
    float* out = (float*)d_out;

    dim3 grid(BATCH / RB * (UNITS / 64));   // 64 bands * 8 u-tiles = 512 blocks
    dim3 block(512);                        // 8 waves
    maxexp_kernel<<<grid, block, 0, stream>>>(x, W, bias, out);
}

// Round 5
// 30.930 us; speedup vs baseline: 1.4499x; 1.0115x over previous
//
#include <hip/hip_runtime.h>

// out[b,u] = tanh( exp( max_i x[b,i]*W[i,u] ) - 1 + bias[u] )
// exp monotonic -> max commutes -> max-times "GEMM" + transcendental epilogue.
//
// Structure: W RESIDENT IN VGPRs (asm-pinned so LLVM cannot demote/remat).
//   Block = 8 waves x 64 units (lane = unit). Wave wv holds W[wv*64..+63][u]
//   in 64 VGPRs. x rows are wave-uniform -> s_load (scalar pipe; no VMEM).
//   Steady state: pure v_mul + v_max3 from registers, zero vector loads.
//   Per 16-row group: 32KB LDS 8-way max combine + exp/tanh epilogue.

#define BATCH 2048
#define INDIM 512
#define UNITS 512

#define KC 64   // k-chunk per wave (W-resident VGPRs)
#define RB 32   // rows per block
#define RG 16   // rows per accumulation group
#define NW 8    // waves per block (NW*KC == INDIM)

__global__ __launch_bounds__(512, 4) void maxexp_kernel(
    const float* __restrict__ x,     // [BATCH][INDIM]
    const float* __restrict__ W,     // [INDIM][UNITS]
    const float* __restrict__ bias,  // [UNITS]
    float* __restrict__ out)         // [BATCH][UNITS]
{
    __shared__ float part[RG][NW][64];   // 32 KB

    // bijective XCD swizzle: all 8 u-tiles of a row-band land on one XCD.
    const int f    = blockIdx.x;          // 0..511
    const int r    = f & 7;
    const int q    = f >> 3;              // 0..63
    const int band = r + 8 * (q & 7);     // 0..63
    const int ut   = q >> 3;              // 0..7

    const int lane = threadIdx.x & 63;
    const int wv   = __builtin_amdgcn_readfirstlane(threadIdx.x >> 6); // 0..7
    const int u    = ut * 64 + lane;      // unit (per-lane)
    const int k0   = wv * KC;             // k-chunk base (uniform)
    const int b0   = band * RB;           // first row (uniform)

    // ---- preload W chunk into registers: W[k0+j][u] ----
    float wreg[KC];
    {
        const float* wp = W + (size_t)k0 * UNITS + u;
#pragma unroll
        for (int j = 0; j < KC; ++j) wreg[j] = wp[(size_t)j * UNITS];
    }
    // Pin: opaque asm makes each element the result of an "instruction" the
    // compiler can't rematerialize -> all 64 stay live in VGPRs.
#pragma unroll
    for (int j = 0; j < KC; ++j) asm volatile("" : "+v"(wreg[j]));

    const float* xb = x + (size_t)b0 * INDIM + k0;   // uniform base
    const float bv  = bias[u];

#pragma unroll 1
    for (int g = 0; g < RB / RG; ++g) {
        float acc[RG];

        // ---- main compute: 16 rows, SGPR(x) * VGPR(W), 4 max-chains/row ----
#pragma unroll
        for (int t = 0; t < RG; ++t) {
            const float* xr = xb + (size_t)(g * RG + t) * INDIM;  // uniform
            float c0 = -3.4e38f, c1 = -3.4e38f, c2 = -3.4e38f, c3 = -3.4e38f;
#pragma unroll
            for (int h = 0; h < 4; ++h) {   // 4 float4 per quarter-chain step
                const float4 a0 = *reinterpret_cast<const float4*>(xr +  0 + 4 * h);
                const float4 a1 = *reinterpret_cast<const float4*>(xr + 16 + 4 * h);
                const float4 a2 = *reinterpret_cast<const float4*>(xr + 32 + 4 * h);
                const float4 a3 = *reinterpret_cast<const float4*>(xr + 48 + 4 * h);
                const int j = 4 * h;
                c0 = fmaxf(fmaxf(c0, a0.x * wreg[ 0 + j]), a0.y * wreg[ 1 + j]);
                c0 = fmaxf(fmaxf(c0, a0.z * wreg[ 2 + j]), a0.w * wreg[ 3 + j]);
                c1 = fmaxf(fmaxf(c1, a1.x * wreg[16 + j]), a1.y * wreg[17 + j]);
                c1 = fmaxf(fmaxf(c1, a1.z * wreg[18 + j]), a1.w * wreg[19 + j]);
                c2 = fmaxf(fmaxf(c2, a2.x * wreg[32 + j]), a2.y * wreg[33 + j]);
                c2 = fmaxf(fmaxf(c2, a2.z * wreg[34 + j]), a2.w * wreg[35 + j]);
                c3 = fmaxf(fmaxf(c3, a3.x * wreg[48 + j]), a3.y * wreg[49 + j]);
                c3 = fmaxf(fmaxf(c3, a3.z * wreg[50 + j]), a3.w * wreg[51 + j]);
            }
            acc[t] = fmaxf(fmaxf(c0, c1), fmaxf(c2, c3));
        }

        // ---- 8-way cross-wave max combine via LDS ----
        __syncthreads();   // protect LDS reuse from previous group's reads
#pragma unroll
        for (int t = 0; t < RG; ++t) part[t][wv][lane] = acc[t];
        __syncthreads();

        // each wave reduces 2 rows, applies epilogue, stores
#pragma unroll
        for (int i = 0; i < 2; ++i) {
            const int t = 2 * wv + i;
            const float p0 = part[t][0][lane], p1 = part[t][1][lane];
            const float p2 = part[t][2][lane], p3 = part[t][3][lane];
            const float p4 = part[t][4][lane], p5 = part[t][5][lane];
            const float p6 = part[t][6][lane], p7 = part[t][7][lane];
            float m = fmaxf(fmaxf(fmaxf(p0, p1), fmaxf(p2, p3)),
                            fmaxf(fmaxf(p4, p5), fmaxf(p6, p7)));
            const float pp = __expf(m) - 1.0f + bv;
            const float e  = __expf(2.0f * pp);
            out[(size_t)(b0 + g * RG + t) * UNITS + u] = 1.0f - 2.0f / (e + 1.0f);
        }
    }
}

extern "C" void kernel_launch(void* const* d_in, const int* in_sizes, int n_in,
                              void* d_out, int out_size, void* d_ws, size_t ws_size,
                              hipStream_t stream) {
    const float* x    = (const float*)d_in[0];
    const float* W    = (const float*)d_in[1];
    const float* bias = (const float*)d_in[2];
    float* out = (float*)d_out;

    dim3 grid(BATCH / RB * (UNITS / 64));   // 64 bands * 8 u-tiles = 512 blocks
    dim3 block(512);                        // 8 waves
    maxexp_kernel<<<grid, block, 0, stream>>>(x, W, bias, out);
}

// Round 6
// 28.058 us; speedup vs baseline: 1.5983x; 1.1023x over previous
//
#include <hip/hip_runtime.h>

// out[b,u] = tanh( exp( max_i x[b,i]*W[i,u] ) - 1 + bias[u] )
// exp monotonic -> max commutes -> max-times "GEMM" + transcendental epilogue.
//
// Occupancy-first structure: 8 waves/SIMD (the R2-R5 stall analysis says the
// per-wave scalar-load drain (~50% duty) is unavoidable; hide it with waves).
//   Block = 16 waves x 64 units (lane = unit). Wave wv holds
//   W[wv*32 .. wv*32+31][u] in 32 pinned VGPRs. x rows are wave-uniform ->
//   s_load. 16-way k-split combined via LDS per 8-row group.
//   VGPR budget ~55 <= 64  ->  __launch_bounds__(1024, 8) = 8 waves/SIMD.

#define BATCH 2048
#define INDIM 512
#define UNITS 512

#define KC 32   // k-chunk per wave (W-resident VGPRs)
#define RB 16   // rows per block
#define RG 8    // rows per accumulation group
#define NW 16   // waves per block (NW*KC == INDIM)

__global__ __launch_bounds__(1024, 8) void maxexp_kernel(
    const float* __restrict__ x,     // [BATCH][INDIM]
    const float* __restrict__ W,     // [INDIM][UNITS]
    const float* __restrict__ bias,  // [UNITS]
    float* __restrict__ out)         // [BATCH][UNITS]
{
    __shared__ float part[RG][NW][64];   // 32 KB

    // XCD swizzle (1024 blocks, round-robin f&7 -> XCD): all 8 u-tiles of a
    // 16-row band land on one XCD; each XCD owns 16 contiguous bands.
    const int f   = blockIdx.x;            // 0..1023
    const int bg  = (f & 7) * 16 + ((f >> 3) & 15);   // band 0..127
    const int ut  = f >> 7;                            // u-tile 0..7

    const int lane = threadIdx.x & 63;
    const int wv   = __builtin_amdgcn_readfirstlane(threadIdx.x >> 6); // 0..15
    const int u    = ut * 64 + lane;       // unit (per-lane)
    const int k0   = wv * KC;              // k-chunk base (uniform)
    const int b0   = bg * RB;              // first row (uniform)

    // ---- preload W chunk into registers: W[k0+j][u], pin in VGPRs ----
    float wreg[KC];
    {
        const float* wp = W + (size_t)k0 * UNITS + u;
#pragma unroll
        for (int j = 0; j < KC; ++j) wreg[j] = wp[(size_t)j * UNITS];
    }
#pragma unroll
    for (int j = 0; j < KC; ++j) asm volatile("" : "+v"(wreg[j]));

    const float* xb = x + (size_t)b0 * INDIM + k0;   // uniform base
    const float bv  = bias[u];

#pragma unroll 1
    for (int g = 0; g < RB / RG; ++g) {
        float acc[RG];

        // ---- compute: 8 rows x 32 k, SGPR(x) * VGPR(W), 2 max-chains ----
#pragma unroll
        for (int t = 0; t < RG; ++t) {
            const float* xr = xb + (size_t)(g * RG + t) * INDIM;  // uniform
            float c0 = -3.4e38f, c1 = -3.4e38f;
#pragma unroll
            for (int h = 0; h < 4; ++h) {
                const float4 a0 = *reinterpret_cast<const float4*>(xr +  0 + 4 * h);
                const float4 a1 = *reinterpret_cast<const float4*>(xr + 16 + 4 * h);
                const int j = 4 * h;
                c0 = fmaxf(fmaxf(c0, a0.x * wreg[ 0 + j]), a0.y * wreg[ 1 + j]);
                c0 = fmaxf(fmaxf(c0, a0.z * wreg[ 2 + j]), a0.w * wreg[ 3 + j]);
                c1 = fmaxf(fmaxf(c1, a1.x * wreg[16 + j]), a1.y * wreg[17 + j]);
                c1 = fmaxf(fmaxf(c1, a1.z * wreg[18 + j]), a1.w * wreg[19 + j]);
            }
            acc[t] = fmaxf(c0, c1);
        }

        // ---- 16-way cross-wave max combine via LDS ----
        __syncthreads();   // protect LDS reuse from previous group's reads
#pragma unroll
        for (int t = 0; t < RG; ++t) part[t][wv][lane] = acc[t];
        __syncthreads();

        // waves 0..7: reduce one row each, epilogue, store
        if (wv < RG) {
            const int t = wv;
            float m = -3.4e38f;
#pragma unroll
            for (int j = 0; j < NW; j += 2)
                m = fmaxf(fmaxf(m, part[t][j][lane]), part[t][j + 1][lane]);
            const float pp = __expf(m) - 1.0f + bv;
            const float e  = __expf(2.0f * pp);
            out[(size_t)(b0 + g * RG + t) * UNITS + u] = 1.0f - 2.0f / (e + 1.0f);
        }
    }
}

extern "C" void kernel_launch(void* const* d_in, const int* in_sizes, int n_in,
                              void* d_out, int out_size, void* d_ws, size_t ws_size,
                              hipStream_t stream) {
    const float* x    = (const float*)d_in[0];
    const float* W    = (const float*)d_in[1];
    const float* bias = (const float*)d_in[2];
    float* out = (float*)d_out;

    dim3 grid(BATCH / RB * (UNITS / 64));   // 128 bands * 8 u-tiles = 1024 blocks
    dim3 block(1024);                       // 16 waves
    maxexp_kernel<<<grid, block, 0, stream>>>(x, W, bias, out);
}

// Round 7
// 26.059 us; speedup vs baseline: 1.7209x; 1.0767x over previous
//
#include <hip/hip_runtime.h>

// out[b,u] = tanh( exp( max_i x[b,i]*W[i,u] ) - 1 + bias[u] )
// exp monotonic -> max commutes -> max-times "GEMM" + transcendental epilogue.
//
// R7: pk-mul + forced-occupancy variant of the W-resident structure.
//   Block = 16 waves x 64 units (lane = unit), RB = 16 rows, single group.
//   Wave wv holds W[wv*32 .. +31][u] as 16 v2f pairs in VGPRs (pinned).
//   x rows are wave-uniform -> s_load to SGPR pairs, consumed directly as the
//   64-bit SGPR operand of v_pk_mul_f32 (x uses ZERO VGPRs).
//   Per row: 16 v_pk_mul_f32 + 16 v_max3_f32 = 32 insts / 32 products.
//   One barrier pair; every wave combines + stores exactly one row.

#define BATCH 2048
#define INDIM 512
#define UNITS 512

#define KC 32   // k-chunk per wave
#define RB 16   // rows per block (= rows per group; 1 group)
#define NW 16   // waves per block

typedef float v2f __attribute__((ext_vector_type(2)));

__global__ __launch_bounds__(1024, 8) void maxexp_kernel(
    const float* __restrict__ x,     // [BATCH][INDIM]
    const float* __restrict__ W,     // [INDIM][UNITS]
    const float* __restrict__ bias,  // [UNITS]
    float* __restrict__ out)         // [BATCH][UNITS]
{
    __shared__ float part[RB][NW][64];   // 64 KB

    // bijective XCD swizzle: XCD (f&7) owns 16 contiguous bands x all u-tiles.
    const int f   = blockIdx.x;                        // 0..1023
    const int bg  = (f & 7) * 16 + ((f >> 3) & 15);    // band 0..127
    const int ut  = f >> 7;                            // u-tile 0..7

    const int lane = threadIdx.x & 63;
    const int wv   = __builtin_amdgcn_readfirstlane(threadIdx.x >> 6); // 0..15
    const int u    = ut * 64 + lane;       // unit (per-lane)
    const int k0   = wv * KC;              // k-chunk base (uniform)
    const int b0   = bg * RB;              // first row (uniform)

    // ---- preload W chunk as v2f pairs: (W[k0+2j][u], W[k0+2j+1][u]) ----
    v2f wp[KC / 2];
    {
        const float* wb = W + (size_t)k0 * UNITS + u;
#pragma unroll
        for (int j = 0; j < KC / 2; ++j) {
            v2f t;
            t.x = wb[(size_t)(2 * j)     * UNITS];
            t.y = wb[(size_t)(2 * j + 1) * UNITS];
            wp[j] = t;
        }
    }
#pragma unroll
    for (int j = 0; j < KC / 2; ++j) asm("" : "+v"(wp[j]));  // pin in VGPRs

    const float* xb = x + (size_t)b0 * INDIM + k0;   // uniform base

    float acc[RB];
#pragma unroll
    for (int t = 0; t < RB; ++t) {
        const v2f* xr = reinterpret_cast<const v2f*>(xb + (size_t)t * INDIM);
        float m0 = -3.4e38f, m1 = -3.4e38f;   // two chains
#pragma unroll
        for (int j = 0; j < KC / 2; j += 2) {
            v2f p0, p1;
            // x pair from SGPRs (one 64-bit scalar operand), W pair from VGPRs
            asm("v_pk_mul_f32 %0, %1, %2" : "=v"(p0) : "s"(xr[j]),     "v"(wp[j]));
            asm("v_pk_mul_f32 %0, %1, %2" : "=v"(p1) : "s"(xr[j + 1]), "v"(wp[j + 1]));
            m0 = fmaxf(fmaxf(m0, p0.x), p0.y);   // -> v_max3_f32
            m1 = fmaxf(fmaxf(m1, p1.x), p1.y);
        }
        acc[t] = fmaxf(m0, m1);
    }

    // ---- 16-way cross-wave max combine via LDS (single barrier pair) ----
#pragma unroll
    for (int t = 0; t < RB; ++t) part[t][wv][lane] = acc[t];
    __syncthreads();

    // wave wv reduces + stores row wv
    {
        const int t = wv;
        float m = -3.4e38f;
#pragma unroll
        for (int j = 0; j < NW; j += 2)
            m = fmaxf(fmaxf(m, part[t][j][lane]), part[t][j + 1][lane]);
        const float pp = __expf(m) - 1.0f + bias[u];
        const float e  = __expf(2.0f * pp);
        out[(size_t)(b0 + t) * UNITS + u] = 1.0f - 2.0f / (e + 1.0f);
    }
}

extern "C" void kernel_launch(void* const* d_in, const int* in_sizes, int n_in,
                              void* d_out, int out_size, void* d_ws, size_t ws_size,
                              hipStream_t stream) {
    const float* x    = (const float*)d_in[0];
    const float* W    = (const float*)d_in[1];
    const float* bias = (const float*)d_in[2];
    float* out = (float*)d_out;

    dim3 grid(BATCH / RB * (UNITS / 64));   // 128 bands * 8 u-tiles = 1024 blocks
    dim3 block(1024);                       // 16 waves
    maxexp_kernel<<<grid, block, 0, stream>>>(x, W, bias, out);
}